// Round 6
// baseline (265.731 us; speedup 1.0000x reference)
//
#include <hip/hip_runtime.h>

// Weighted BCE mean-reduction, N = 33,554,432 fp32 + int32 labels.
// History: R1/R2 ~106 us = 2.4 TB/s (L1-allocate path cap, structure-
// invariant). R4: nt loads bypass L1 -> ~80 us = 3.2 TB/s (new plateau,
// also structure-invariant: R5's 4-wide MLP = R4's 2-wide exactly).
// Fabric itself does 6.9 TB/s (harness fills). R6 theory: the 2.4 and 3.2
// TB/s walls are caps of two DIFFERENT fill paths (L1-allocate vs
// L1-bypass). Split traffic: x -> nt path, y -> regular cached path.
// If paths overlap, kernel ~= max(128/3.2, 128/2.4) ~= 53 us.

#define WBCE_BLOCK 256
#define WBCE_GRID  2048            // 256 CUs x 8 blocks/CU = 32 waves/CU (max)
#define WBCE_STRIDE (WBCE_GRID * WBCE_BLOCK)   // 524288 threads
#define WBCE_ITERS 16              // n4 / WBCE_STRIDE when N = 33554432

typedef float fx4 __attribute__((ext_vector_type(4)));
typedef int   ix4 __attribute__((ext_vector_type(4)));

__device__ __forceinline__ float wbce_elem(float x, int y, float lw0, float lw1) {
    // returns w * ln(t) with lw = w*ln2 pre-folded: lw_sel * log2(t)
    float t  = (y == 1) ? x : (1.0f - x);
    float lw = (y == 1) ? lw1 : lw0;
    return lw * __log2f(t);
}

__device__ __forceinline__ float wbce_quad(fx4 xv, ix4 yv, float lw0, float lw1) {
    float a = wbce_elem(xv.x, yv.x, lw0, lw1);
    float b = wbce_elem(xv.y, yv.y, lw0, lw1);
    float c = wbce_elem(xv.z, yv.z, lw0, lw1);
    float d = wbce_elem(xv.w, yv.w, lw0, lw1);
    return (a + b) + (c + d);
}

__global__ __launch_bounds__(WBCE_BLOCK) void weightedBCE_75582834475452_kernel(
    const fx4* __restrict__ x4,
    const ix4* __restrict__ y4,
    const float* __restrict__ weights,
    float*       __restrict__ out,
    int n4, int n, float inv_n)
{
    const float ln2 = 0.69314718055994530942f;
    const float lw0 = weights[0] * ln2;
    const float lw1 = weights[1] * ln2;

    float acc = 0.0f;  // accumulates w * ln(t); final loss = -acc
    const int tid = blockIdx.x * WBCE_BLOCK + threadIdx.x;

    if (n4 == WBCE_ITERS * WBCE_STRIDE) {
        // Split-path: x through the nt (L1-bypass) fill path, y through the
        // regular (L1-allocate) fill path — theory: caps are per-path and
        // the two streams overlap instead of sharing one 3.2 TB/s queue.
        #pragma unroll
        for (int g = 0; g < WBCE_ITERS / 2; ++g) {
            const int base = tid + g * 2 * WBCE_STRIDE;
            fx4 xa = __builtin_nontemporal_load(&x4[base + 0 * WBCE_STRIDE]);
            fx4 xb = __builtin_nontemporal_load(&x4[base + 1 * WBCE_STRIDE]);
            ix4 ya = y4[base + 0 * WBCE_STRIDE];   // regular cached load
            ix4 yb = y4[base + 1 * WBCE_STRIDE];   // regular cached load
            acc += wbce_quad(xa, ya, lw0, lw1);
            acc += wbce_quad(xb, yb, lw0, lw1);
        }
    } else {
        // Generic fallback (grid-stride) — correctness for any N.
        for (int i = tid; i < n4; i += WBCE_STRIDE) {
            fx4 xv = __builtin_nontemporal_load(&x4[i]);
            ix4 yv = y4[i];
            acc += wbce_quad(xv, yv, lw0, lw1);
        }
        const float* xs = (const float*)x4;
        const int*   ys = (const int*)y4;
        for (int i = n4 * 4 + tid; i < n; i += WBCE_STRIDE) {
            acc += wbce_elem(xs[i], ys[i], lw0, lw1);
        }
    }

    // wave-64 butterfly reduce
    #pragma unroll
    for (int off = 32; off > 0; off >>= 1)
        acc += __shfl_down(acc, off, 64);

    __shared__ float smem[WBCE_BLOCK / 64];
    const int lane = threadIdx.x & 63;
    const int wave = threadIdx.x >> 6;
    if (lane == 0) smem[wave] = acc;
    __syncthreads();

    if (threadIdx.x == 0) {
        float total = 0.0f;
        #pragma unroll
        for (int w = 0; w < WBCE_BLOCK / 64; ++w) total += smem[w];
        // loss = -sum(w*ln t); pre-scale by 1/N so d_out holds the mean
        atomicAdd(out, -total * inv_n);
    }
}

extern "C" void kernel_launch(void* const* d_in, const int* in_sizes, int n_in,
                              void* d_out, int out_size, void* d_ws, size_t ws_size,
                              hipStream_t stream) {
    const float* x = (const float*)d_in[0];
    const int*   y = (const int*)d_in[1];
    const float* w = (const float*)d_in[2];
    float* out = (float*)d_out;
    const int n  = in_sizes[0];
    const int n4 = n >> 2;

    // d_out is poisoned to 0xAA before every timed replay — zero it on-stream
    // (hipMemsetAsync is graph-capture safe).
    (void)hipMemsetAsync(out, 0, sizeof(float), stream);

    weightedBCE_75582834475452_kernel<<<WBCE_GRID, WBCE_BLOCK, 0, stream>>>(
        (const fx4*)x, (const ix4*)y, w, out, n4, n, 1.0f / (float)n);
}

// Round 7
// 260.738 us; speedup vs baseline: 1.0192x; 1.0192x over previous
//
#include <hip/hip_runtime.h>

// Weighted BCE mean-reduction, N = 33,554,432 fp32 + int32 labels.
// FINAL (R5 revert). History:
//   R1/R2: cached loads, ~106 us = 2.4 TB/s (L1-allocate fill-path cap;
//          structure-invariant — MLP width did nothing).
//   R4/R5: all-nontemporal loads bypass L1 -> ~77-78 us = 3.24 TB/s
//          (MLP width again null: R4 2-wide == R5 4-wide to 0.05 us).
//   R6:    mixed nt/cached split-path -> 79.5 us (regression; paths don't
//          overlap — falsified the per-path-cap theory).
// Read-path ceiling evidence: D2D copy read stream 3.15 TB/s, RMSNorm read
// component ~3.3, this kernel 3.24 — all converge at ~3.2 TB/s while pure
// writes do 6.9 TB/s. 256 MB / 3.25 TB/s = 78.8 us floor; we're at it.

#define WBCE_BLOCK 256
#define WBCE_GRID  2048            // 256 CUs x 8 blocks/CU = 32 waves/CU (max)
#define WBCE_STRIDE (WBCE_GRID * WBCE_BLOCK)   // 524288 threads
#define WBCE_ITERS 16              // n4 / WBCE_STRIDE when N = 33554432

typedef float fx4 __attribute__((ext_vector_type(4)));
typedef int   ix4 __attribute__((ext_vector_type(4)));

__device__ __forceinline__ float wbce_elem(float x, int y, float lw0, float lw1) {
    // returns w * ln(t) with lw = w*ln2 pre-folded: lw_sel * log2(t)
    float t  = (y == 1) ? x : (1.0f - x);
    float lw = (y == 1) ? lw1 : lw0;
    return lw * __log2f(t);
}

__device__ __forceinline__ float wbce_quad(fx4 xv, ix4 yv, float lw0, float lw1) {
    float a = wbce_elem(xv.x, yv.x, lw0, lw1);
    float b = wbce_elem(xv.y, yv.y, lw0, lw1);
    float c = wbce_elem(xv.z, yv.z, lw0, lw1);
    float d = wbce_elem(xv.w, yv.w, lw0, lw1);
    return (a + b) + (c + d);
}

__global__ __launch_bounds__(WBCE_BLOCK) void weightedBCE_75582834475452_kernel(
    const fx4* __restrict__ x4,
    const ix4* __restrict__ y4,
    const float* __restrict__ weights,
    float*       __restrict__ out,
    int n4, int n, float inv_n)
{
    const float ln2 = 0.69314718055994530942f;
    const float lw0 = weights[0] * ln2;
    const float lw1 = weights[1] * ln2;

    float acc = 0.0f;  // accumulates w * ln(t); final loss = -acc
    const int tid = blockIdx.x * WBCE_BLOCK + threadIdx.x;

    if (n4 == WBCE_ITERS * WBCE_STRIDE) {
        // All-nontemporal: best measured config (3.24 TB/s read).
        #pragma unroll
        for (int g = 0; g < WBCE_ITERS / 4; ++g) {
            const int base = tid + g * 4 * WBCE_STRIDE;
            fx4 xa = __builtin_nontemporal_load(&x4[base + 0 * WBCE_STRIDE]);
            fx4 xb = __builtin_nontemporal_load(&x4[base + 1 * WBCE_STRIDE]);
            fx4 xc = __builtin_nontemporal_load(&x4[base + 2 * WBCE_STRIDE]);
            fx4 xd = __builtin_nontemporal_load(&x4[base + 3 * WBCE_STRIDE]);
            ix4 ya = __builtin_nontemporal_load(&y4[base + 0 * WBCE_STRIDE]);
            ix4 yb = __builtin_nontemporal_load(&y4[base + 1 * WBCE_STRIDE]);
            ix4 yc = __builtin_nontemporal_load(&y4[base + 2 * WBCE_STRIDE]);
            ix4 yd = __builtin_nontemporal_load(&y4[base + 3 * WBCE_STRIDE]);
            acc += wbce_quad(xa, ya, lw0, lw1);
            acc += wbce_quad(xb, yb, lw0, lw1);
            acc += wbce_quad(xc, yc, lw0, lw1);
            acc += wbce_quad(xd, yd, lw0, lw1);
        }
    } else {
        // Generic fallback (grid-stride) — correctness for any N.
        for (int i = tid; i < n4; i += WBCE_STRIDE) {
            fx4 xv = __builtin_nontemporal_load(&x4[i]);
            ix4 yv = __builtin_nontemporal_load(&y4[i]);
            acc += wbce_quad(xv, yv, lw0, lw1);
        }
        const float* xs = (const float*)x4;
        const int*   ys = (const int*)y4;
        for (int i = n4 * 4 + tid; i < n; i += WBCE_STRIDE) {
            acc += wbce_elem(xs[i], ys[i], lw0, lw1);
        }
    }

    // wave-64 butterfly reduce
    #pragma unroll
    for (int off = 32; off > 0; off >>= 1)
        acc += __shfl_down(acc, off, 64);

    __shared__ float smem[WBCE_BLOCK / 64];
    const int lane = threadIdx.x & 63;
    const int wave = threadIdx.x >> 6;
    if (lane == 0) smem[wave] = acc;
    __syncthreads();

    if (threadIdx.x == 0) {
        float total = 0.0f;
        #pragma unroll
        for (int w = 0; w < WBCE_BLOCK / 64; ++w) total += smem[w];
        // loss = -sum(w*ln t); pre-scale by 1/N so d_out holds the mean
        atomicAdd(out, -total * inv_n);
    }
}

extern "C" void kernel_launch(void* const* d_in, const int* in_sizes, int n_in,
                              void* d_out, int out_size, void* d_ws, size_t ws_size,
                              hipStream_t stream) {
    const float* x = (const float*)d_in[0];
    const int*   y = (const int*)d_in[1];
    const float* w = (const float*)d_in[2];
    float* out = (float*)d_out;
    const int n  = in_sizes[0];
    const int n4 = n >> 2;

    // d_out is poisoned to 0xAA before every timed replay — zero it on-stream
    // (hipMemsetAsync is graph-capture safe).
    (void)hipMemsetAsync(out, 0, sizeof(float), stream);

    weightedBCE_75582834475452_kernel<<<WBCE_GRID, WBCE_BLOCK, 0, stream>>>(
        (const fx4*)x, (const ix4*)y, w, out, n4, n, 1.0f / (float)n);
}